// Round 19
// baseline (49.109 us; speedup 1.0000x reference)
//
#include <hip/hip_runtime.h>
#include <math.h>

#define D_DIM   128
#define NCHART  64
#define PADR    132      // padded row stride: bank (132*row + col) spreads rows
#define BPC     8        // blocks per chart -> 512 blocks, 2/CU at 72.7KB LDS
#define NS      2        // samples per wave batch (r9-verified, no spill)
#define LCAP    256      // per-chart list cap (mean 64)
#define MAXNORM 0.99f

typedef float f32x4 __attribute__((ext_vector_type(4)));

// ---- DPP reductions (VALU pipe; r18-verified) ----
template <int CTRL, int MASK>
__device__ __forceinline__ float dpp_add(float x) {
  int y = __builtin_amdgcn_update_dpp(0, __float_as_int(x), CTRL, MASK, 0xf, true);
  return x + __int_as_float(y);
}
__device__ __forceinline__ float dpp_sum64(float x) {
  x = dpp_add<0x111, 0xf>(x);
  x = dpp_add<0x112, 0xf>(x);
  x = dpp_add<0x114, 0xf>(x);
  x = dpp_add<0x118, 0xf>(x);
  x = dpp_add<0x142, 0xa>(x);
  x = dpp_add<0x143, 0xc>(x);
  return __int_as_float(__builtin_amdgcn_readlane(__float_as_int(x), 63));
}

// ---- deterministic index-ordered list build (r11-verified): all BPC blocks of
// a chart derive the IDENTICAL ascending list, so slot partitioning is exact.
__device__ __forceinline__ int build_list(const int* __restrict__ idx, int B,
                                          int chart, int* list, int* wc,
                                          int w, int l, int tid) {
  int tot = 0;
  const unsigned long long below = (1ull << l) - 1;
  for (int b0 = 0; b0 < B; b0 += 256) {
    int b = b0 + tid;
    bool m = (b < B) && (idx[b] == chart);
    unsigned long long mask = __ballot(m);
    if (l == 0) wc[w] = __popcll(mask);
    __syncthreads();
    int base = tot;
#pragma unroll
    for (int ww = 0; ww < 4; ++ww) if (ww < w) base += wc[ww];
    int pos = base + __popcll(mask & below);
    if (m && pos < LCAP) list[pos] = b;
    tot += wc[0] + wc[1] + wc[2] + wc[3];
    __syncthreads();
  }
  return tot < LCAP ? tot : LCAP;
}

// ---- S1: group by tgt; v = R_tgt @ mobius(-proj(c_src), proj(z)) -> out ----
__global__ __launch_bounds__(256) void k_s1(
    const float* __restrict__ z_n, const float* __restrict__ centers,
    const float* __restrict__ rot, const int* __restrict__ src_idx,
    const int* __restrict__ tgt_idx, float* __restrict__ vout, int B)
{
  __shared__ float R[D_DIM * PADR];     // 67.6 KB
  __shared__ float zs[4][NS][D_DIM];    // 4 KB
  __shared__ int list[LCAP];
  __shared__ int wc[4];

  const int tid = threadIdx.x;
  const int chart = blockIdx.x >> 3;
  const int q = blockIdx.x & 7;
  const int w = tid >> 6, l = tid & 63;

  const int n = build_list(tgt_idx, B, chart, list, wc, w, l, tid);
  if (q * 4 * NS >= n) return;          // block-uniform, after all syncs

  const f32x4* G4 = (const f32x4*)(rot + (size_t)chart * D_DIM * D_DIM);
  for (int g = tid; g < 4096; g += 256) {
    int r = g >> 5, J = g & 31;
    *(f32x4*)&R[r * PADR + 4 * J] = G4[g];
  }
  __syncthreads();

  for (int s0 = (q * 4 + w) * NS; s0 < n; s0 += 32 * NS) {
    const int kmax = min(NS, n - s0);   // wave-uniform
    int bs[NS];
#pragma unroll
    for (int k = 0; k < NS; ++k) {
      if (k < kmax) {
        int b = list[s0 + k];
        bs[k] = b;
        float a  = z_n[(size_t)b * D_DIM + l];
        float bb = z_n[(size_t)b * D_DIM + l + 64];
        float nz = sqrtf(dpp_sum64(a * a + bb * bb));
        if (nz > MAXNORM) { float sc = MAXNORM / nz; a *= sc; bb *= sc; }

        int si = src_idx[b];
        float c0 = centers[(size_t)si * D_DIM + l];
        float c1 = centers[(size_t)si * D_DIM + l + 64];
        float ncn = sqrtf(dpp_sum64(c0 * c0 + c1 * c1));
        if (ncn > MAXNORM) { float sc = MAXNORM / ncn; c0 *= sc; c1 *= sc; }
        c0 = -c0; c1 = -c1;                        // x = -c_source

        float x2 = dpp_sum64(c0 * c0 + c1 * c1);
        float y2 = dpp_sum64(a * a + bb * bb);
        float xy = dpp_sum64(c0 * a + c1 * bb);
        float nx  = 1.0f + 2.0f * xy + y2;
        float ny  = 1.0f - x2;
        float inv = 1.0f / fmaxf(1.0f + 2.0f * xy + x2 * y2, 1e-15f);
        zs[w][k][l]      = (nx * c0 + ny * a)  * inv;
        zs[w][k][l + 64] = (nx * c1 + ny * bb) * inv;
      }
    }
    asm volatile("s_waitcnt lgkmcnt(0)" ::: "memory");

    // v_i = sum_j R[i][j] z_j ; lane owns rows l, l+64; NS shares R reads.
    // k >= kmax slots read stale LDS -> garbage acc, never stored.
    float acc0[NS] = {}, acc1[NS] = {};
#pragma unroll 4
    for (int Jg = 0; Jg < 32; ++Jg) {
      f32x4 a0 = *(const f32x4*)&R[l * PADR + 4 * Jg];
      f32x4 a1 = *(const f32x4*)&R[(l + 64) * PADR + 4 * Jg];
#pragma unroll
      for (int k = 0; k < NS; ++k) {
        f32x4 zv = *(const f32x4*)&zs[w][k][4 * Jg];
#pragma unroll
        for (int m = 0; m < 4; ++m) {
          acc0[k] = fmaf(a0[m], zv[m], acc0[k]);
          acc1[k] = fmaf(a1[m], zv[m], acc1[k]);
        }
      }
    }
#pragma unroll
    for (int k = 0; k < NS; ++k) {
      if (k < kmax) {
        vout[(size_t)bs[k] * D_DIM + l]      = acc0[k];
        vout[(size_t)bs[k] * D_DIM + l + 64] = acc1[k];
      }
    }
  }
}

// ---- S2: group by src; out = proj(mobius(proj(c_tgt), R_src^T @ v)) ----
__global__ __launch_bounds__(256) void k_s2(
    const float* __restrict__ centers, const float* __restrict__ rot,
    const int* __restrict__ src_idx, const int* __restrict__ tgt_idx,
    float* __restrict__ io, int B)
{
  __shared__ float R[D_DIM * PADR];
  __shared__ float vs[4][NS][D_DIM];
  __shared__ int list[LCAP];
  __shared__ int wc[4];

  const int tid = threadIdx.x;
  const int chart = blockIdx.x >> 3;
  const int q = blockIdx.x & 7;
  const int w = tid >> 6, l = tid & 63;

  const int n = build_list(src_idx, B, chart, list, wc, w, l, tid);
  if (q * 4 * NS >= n) return;

  const f32x4* G4 = (const f32x4*)(rot + (size_t)chart * D_DIM * D_DIM);
  for (int g = tid; g < 4096; g += 256) {
    int r = g >> 5, J = g & 31;
    *(f32x4*)&R[r * PADR + 4 * J] = G4[g];
  }
  __syncthreads();

  for (int s0 = (q * 4 + w) * NS; s0 < n; s0 += 32 * NS) {
    const int kmax = min(NS, n - s0);
    int bs[NS];
#pragma unroll
    for (int k = 0; k < NS; ++k) {
      if (k < kmax) {
        int b = list[s0 + k];
        bs[k] = b;
        vs[w][k][l]      = io[(size_t)b * D_DIM + l];
        vs[w][k][l + 64] = io[(size_t)b * D_DIM + l + 64];
      }
    }
    asm volatile("s_waitcnt lgkmcnt(0)" ::: "memory");

    // w_i = sum_j R[j][i] v_j ; column reads (2 lanes/bank = free); NS shares.
    float acc0[NS] = {}, acc1[NS] = {};
#pragma unroll 8
    for (int j = 0; j < 128; ++j) {
      float r0 = R[j * PADR + l];
      float r1 = R[j * PADR + l + 64];
      float vj0 = vs[w][0][j];
      float vj1 = vs[w][1][j];
      acc0[0] = fmaf(r0, vj0, acc0[0]);
      acc1[0] = fmaf(r1, vj0, acc1[0]);
      acc0[1] = fmaf(r0, vj1, acc0[1]);
      acc1[1] = fmaf(r1, vj1, acc1[1]);
    }

#pragma unroll
    for (int k = 0; k < NS; ++k) {
      if (k < kmax) {
        int b = bs[k];
        int ti = tgt_idx[b];
        float c0 = centers[(size_t)ti * D_DIM + l];
        float c1 = centers[(size_t)ti * D_DIM + l + 64];
        float ncn = sqrtf(dpp_sum64(c0 * c0 + c1 * c1));
        if (ncn > MAXNORM) { float sc = MAXNORM / ncn; c0 *= sc; c1 *= sc; }

        float w0 = acc0[k], w1 = acc1[k];
        float x2 = dpp_sum64(c0 * c0 + c1 * c1);
        float y2 = dpp_sum64(w0 * w0 + w1 * w1);
        float xy = dpp_sum64(c0 * w0 + c1 * w1);
        float nx  = 1.0f + 2.0f * xy + y2;
        float ny  = 1.0f - x2;
        float inv = 1.0f / fmaxf(1.0f + 2.0f * xy + x2 * y2, 1e-15f);
        float o0 = (nx * c0 + ny * w0) * inv;
        float o1 = (nx * c1 + ny * w1) * inv;

        float no = sqrtf(dpp_sum64(o0 * o0 + o1 * o1));
        if (no > MAXNORM) { float sc = MAXNORM / no; o0 *= sc; o1 *= sc; }

        io[(size_t)b * D_DIM + l]      = o0;
        io[(size_t)b * D_DIM + l + 64] = o1;
      }
    }
  }
}

extern "C" void kernel_launch(void* const* d_in, const int* in_sizes, int n_in,
                              void* d_out, int out_size, void* d_ws, size_t ws_size,
                              hipStream_t stream) {
  const float* z_n     = (const float*)d_in[0];
  const float* centers = (const float*)d_in[1];
  const float* rot     = (const float*)d_in[2];
  const int*   src     = (const int*)d_in[3];
  const int*   tgt     = (const int*)d_in[4];
  float* out = (float*)d_out;
  const int B = in_sizes[3];

  dim3 grid(NCHART * BPC), block(256);
  k_s1<<<grid, block, 0, stream>>>(z_n, centers, rot, src, tgt, out, B);
  k_s2<<<grid, block, 0, stream>>>(centers, rot, src, tgt, out, B);
}

// Round 24
// 41.374 us; speedup vs baseline: 1.1870x; 1.1870x over previous
//
#include <hip/hip_runtime.h>
#include <math.h>

#define D_DIM   128
#define NCHART  64
#define NS      2        // same-chart samples sharing each matrix load
#define LCAP    160      // per-chart list cap (Poisson mean 64, 12 sigma)
#define MAXNORM 0.99f
#define MN2     (0.99f * 0.99f)

typedef float f32x4 __attribute__((ext_vector_type(4)));

// ---- DPP reductions (VALU pipe; r18-verified) ----
template <int CTRL, int MASK>
__device__ __forceinline__ float dpp_add(float x) {
  int y = __builtin_amdgcn_update_dpp(0, __float_as_int(x), CTRL, MASK, 0xf, true);
  return x + __int_as_float(y);
}
__device__ __forceinline__ float dpp_sum64(float x) {
  x = dpp_add<0x111, 0xf>(x);
  x = dpp_add<0x112, 0xf>(x);
  x = dpp_add<0x114, 0xf>(x);
  x = dpp_add<0x118, 0xf>(x);
  x = dpp_add<0x142, 0xa>(x);
  x = dpp_add<0x143, 0xc>(x);
  return __int_as_float(__builtin_amdgcn_readlane(__float_as_int(x), 63));
}
// lane31 = sum(lanes 0..31), lane63 = sum(lanes 32..63)
__device__ __forceinline__ float dpp_sum32(float x) {
  x = dpp_add<0x111, 0xf>(x);
  x = dpp_add<0x112, 0xf>(x);
  x = dpp_add<0x114, 0xf>(x);
  x = dpp_add<0x118, 0xf>(x);
  x = dpp_add<0x142, 0xa>(x);
  return x;
}

// ---- setup: 128 blocks x 1 wave; block c<64 builds tgt-list(c), else src-list.
// All loads prefetched (independent), ballot compaction, zero barriers.
// ws ints: [0..127]=counts (tgt 0-63, src 64-127); lists at 128 + bid*LCAP.
__global__ __launch_bounds__(64) void k_setup(
    const int* __restrict__ src, const int* __restrict__ tgt,
    int* __restrict__ ws, int B)
{
  const int bid = blockIdx.x;
  const int chart = bid & 63;
  const int* __restrict__ idx = (bid >= NCHART) ? src : tgt;
  int* list = ws + 128 + bid * LCAP;
  const int l = threadIdx.x;
  const unsigned long long below = (1ull << l) - 1;

  int4 v[16];
#pragma unroll
  for (int k = 0; k < 16; ++k) {
    int g = l + 64 * k;
    v[k] = (4 * g + 3 < B) ? ((const int4*)idx)[g] : make_int4(-1, -1, -1, -1);
  }
  int tot = 0;
#pragma unroll
  for (int k = 0; k < 16; ++k) {
    int g = l + 64 * k;
    int e4[4] = { v[k].x, v[k].y, v[k].z, v[k].w };
#pragma unroll
    for (int e = 0; e < 4; ++e) {
      bool m = (e4[e] == chart);
      unsigned long long mask = __ballot(m);
      int pos = tot + __popcll(mask & below);
      if (m && pos < LCAP) list[pos] = 4 * g + e;
      tot += __popcll(mask);
    }
  }
  if (l == 0) ws[bid] = min(tot, LCAP);
}

// ---- S1: tgt-grouped; v = R_tgt @ mobius(-proj(c_src), proj(z)) -> vout
// block = one sample-pair slot (chart, q); 4 waves = 4 row-quarters.
__global__ __launch_bounds__(256) void k_s1(
    const float* __restrict__ z_n, const float* __restrict__ centers,
    const float* __restrict__ rot, const int* __restrict__ src_idx,
    const int* __restrict__ ws, float* __restrict__ vout)
{
  __shared__ float zs[2][NS][D_DIM];   // parity-buffered z_global

  const int tid = threadIdx.x;
  const int w = tid >> 6, l = tid & 63;
  const int chart = blockIdx.x >> 5, q = blockIdx.x & 31;
  const int n = ws[chart];
  const int s0b = q * NS;
  if (n <= s0b) return;                // block-uniform (before any barrier)
  const int T = (n - s0b - 1) / (32 * NS) + 1;
  const int* __restrict__ list = ws + 128 + chart * LCAP;
  const float* __restrict__ Rt = rot + ((size_t)chart << 14);
  const int h = l >> 5, qd = l & 31;

  for (int t = 0; t < T; ++t) {
    const int s0 = s0b + t * 32 * NS;
    const int kmax = min(NS, n - s0);  // >=1, block-uniform
    const int par = t & 1;

    if (w == 0) {                      // Mobius A (r18-verbatim), wave 0 only
      for (int k = 0; k < kmax; ++k) {
        int b = list[s0 + k];
        float2 z = ((const float2*)(z_n + (size_t)b * D_DIM))[l];
        int si = src_idx[b];
        float2 c = ((const float2*)(centers + (size_t)si * D_DIM))[l];
        float y2p = dpp_sum64(z.x * z.x + z.y * z.y);
        float x2p = dpp_sum64(c.x * c.x + c.y * c.y);
        float cz  = dpp_sum64(c.x * z.x + c.y * z.y);
        float sz = 1.0f, y2 = y2p;
        if (y2p > MN2) { sz = MAXNORM / sqrtf(y2p); y2 = MN2; }
        float sc = 1.0f, x2 = x2p;
        if (x2p > MN2) { sc = MAXNORM / sqrtf(x2p); x2 = MN2; }
        float xy  = -(sc * sz) * cz;   // x = -c_source
        float nx  = 1.0f + 2.0f * xy + y2;
        float ny  = 1.0f - x2;
        float inv = 1.0f / fmaxf(1.0f + 2.0f * xy + x2 * y2, 1e-15f);
        float2 zg;
        zg.x = (nx * (-sc * c.x) + ny * (sz * z.x)) * inv;
        zg.y = (nx * (-sc * c.y) + ny * (sz * z.y)) * inv;
        ((float2*)zs[par][k])[l] = zg;
      }
    }
    __syncthreads();

    // matvec quarter: wave w owns rows [32w, 32w+32), 2 rows/iter (1KB coalesced)
    const int b0 = list[s0];
    const int b1 = list[s0 + (kmax > 1 ? 1 : 0)];
    const f32x4 zc0 = *(const f32x4*)&zs[par][0][4 * qd];
    const f32x4 zc1 = *(const f32x4*)&zs[par][kmax > 1 ? 1 : 0][4 * qd];
#pragma unroll 4
    for (int tt = 0; tt < 16; ++tt) {
      const int r = 32 * w + 2 * tt + h;
      f32x4 rr = *(const f32x4*)&Rt[(size_t)r * D_DIM + 4 * qd];
      float p0 = fmaf(rr[3], zc0[3], fmaf(rr[2], zc0[2], fmaf(rr[1], zc0[1], rr[0] * zc0[0])));
      float p1 = fmaf(rr[3], zc1[3], fmaf(rr[2], zc1[2], fmaf(rr[1], zc1[1], rr[0] * zc1[0])));
      p0 = dpp_sum32(p0);
      p1 = dpp_sum32(p1);
      if (qd == 31) {
        vout[(size_t)b0 * D_DIM + r] = p0;
        if (kmax > 1) vout[(size_t)b1 * D_DIM + r] = p1;
      }
    }
    __syncthreads();                   // zs[par] reuse safety at t+2
  }
}

// ---- S2: src-grouped; out = proj(mobius(proj(c_tgt), R_src^T @ v))
__global__ __launch_bounds__(256) void k_s2(
    const float* __restrict__ centers, const float* __restrict__ rot,
    const int* __restrict__ tgt_idx, const int* __restrict__ ws,
    float* __restrict__ io)
{
  __shared__ float vs[2][NS][D_DIM];
  __shared__ float wb[2][NS][D_DIM];

  const int tid = threadIdx.x;
  const int w = tid >> 6, l = tid & 63;
  const int chart = blockIdx.x >> 5, q = blockIdx.x & 31;
  const int n = ws[NCHART + chart];
  const int s0b = q * NS;
  if (n <= s0b) return;
  const int T = (n - s0b - 1) / (32 * NS) + 1;
  const int* __restrict__ list = ws + 128 + (NCHART + chart) * LCAP;
  const float* __restrict__ Rs = rot + ((size_t)chart << 14);
  const int jh = l >> 5, i32 = l & 31;

  for (int t = 0; t < T; ++t) {
    const int s0 = s0b + t * 32 * NS;
    const int kmax = min(NS, n - s0);
    const int par = t & 1;

    if (w < kmax) {                    // wave k loads sample k's v
      int b = list[s0 + w];
      ((float2*)vs[par][w])[l] = ((const float2*)(io + (size_t)b * D_DIM))[l];
    }
    __syncthreads();

    // matvec: wave w owns outputs i in [32w,32w+32); lane half splits j.
    float a0 = 0.0f, a1 = 0.0f;
#pragma unroll 8
    for (int jj = 0; jj < 64; ++jj) {
      const int j = 64 * jh + jj;
      float rv = Rs[(size_t)j * D_DIM + 32 * w + i32];
      a0 = fmaf(rv, vs[par][0][j], a0);
      a1 = fmaf(rv, vs[par][1][j], a1);   // garbage if kmax==1; never stored
    }
    a0 += __shfl_xor(a0, 32, 64);
    a1 += __shfl_xor(a1, 32, 64);
    if (jh == 0) {
      wb[par][0][32 * w + i32] = a0;
      wb[par][1][32 * w + i32] = a1;
    }
    __syncthreads();

    if (w == 0) {                      // Mobius B + projection (r18-verbatim)
      for (int k = 0; k < kmax; ++k) {
        int b = list[s0 + k];
        int ti = tgt_idx[b];
        float2 wv = ((const float2*)wb[par][k])[l];
        float2 tv = ((const float2*)(centers + (size_t)ti * D_DIM))[l];
        float t2p = dpp_sum64(tv.x * tv.x + tv.y * tv.y);
        float w2  = dpp_sum64(wv.x * wv.x + wv.y * wv.y);
        float tw  = dpp_sum64(tv.x * wv.x + tv.y * wv.y);
        float st = 1.0f, x2 = t2p;
        if (t2p > MN2) { st = MAXNORM / sqrtf(t2p); x2 = MN2; }
        float xy  = st * tw;           // x = +c_target
        float nx  = 1.0f + 2.0f * xy + w2;
        float ny  = 1.0f - x2;
        float inv = 1.0f / fmaxf(1.0f + 2.0f * xy + x2 * w2, 1e-15f);
        float o0 = (nx * (st * tv.x) + ny * wv.x) * inv;
        float o1 = (nx * (st * tv.y) + ny * wv.y) * inv;
        float no2 = dpp_sum64(o0 * o0 + o1 * o1);
        if (no2 > MN2) { float s = MAXNORM / sqrtf(no2); o0 *= s; o1 *= s; }
        float2 o; o.x = o0; o.y = o1;
        ((float2*)(io + (size_t)b * D_DIM))[l] = o;
      }
    }
  }
}

extern "C" void kernel_launch(void* const* d_in, const int* in_sizes, int n_in,
                              void* d_out, int out_size, void* d_ws, size_t ws_size,
                              hipStream_t stream) {
  const float* z_n     = (const float*)d_in[0];
  const float* centers = (const float*)d_in[1];
  const float* rot     = (const float*)d_in[2];
  const int*   src     = (const int*)d_in[3];
  const int*   tgt     = (const int*)d_in[4];
  float* out = (float*)d_out;
  int* ws = (int*)d_ws;
  const int B = in_sizes[3];

  k_setup<<<dim3(128), dim3(64), 0, stream>>>(src, tgt, ws, B);
  k_s1<<<dim3(NCHART * 32), dim3(256), 0, stream>>>(z_n, centers, rot, src, ws, out);
  k_s2<<<dim3(NCHART * 32), dim3(256), 0, stream>>>(centers, rot, tgt, ws, out);
}

// Round 25
// 29.514 us; speedup vs baseline: 1.6639x; 1.4019x over previous
//
#include <hip/hip_runtime.h>
#include <math.h>

#define D_DIM   128
#define MAXNORM 0.99f
#define MN2     (0.99f * 0.99f)

typedef float f32x4 __attribute__((ext_vector_type(4)));

// DPP-based reductions: VALU pipe only (r18-verified).
template <int CTRL, int MASK>
__device__ __forceinline__ float dpp_add(float x) {
  int y = __builtin_amdgcn_update_dpp(0, __float_as_int(x), CTRL, MASK, 0xf, true);
  return x + __int_as_float(y);
}
__device__ __forceinline__ float dpp_sum64(float x) {
  x = dpp_add<0x111, 0xf>(x);   // row_shr:1
  x = dpp_add<0x112, 0xf>(x);   // row_shr:2
  x = dpp_add<0x114, 0xf>(x);   // row_shr:4
  x = dpp_add<0x118, 0xf>(x);   // row_shr:8
  x = dpp_add<0x142, 0xa>(x);   // row_bcast15
  x = dpp_add<0x143, 0xc>(x);   // row_bcast31
  return __int_as_float(__builtin_amdgcn_readlane(__float_as_int(x), 63));
}
__device__ __forceinline__ float dpp_sum32(float x) {
  x = dpp_add<0x111, 0xf>(x);
  x = dpp_add<0x112, 0xf>(x);
  x = dpp_add<0x114, 0xf>(x);
  x = dpp_add<0x118, 0xf>(x);
  x = dpp_add<0x142, 0xa>(x);
  return x;
}

// 2 samples per block, 2 waves per sample (r18 structure, 33.7us verified).
// launch_bounds(256,8): force 8 waves/SIMD so the stage-B unroll bump cannot
// cost occupancy (VGPR capped at 64).
__global__ __launch_bounds__(256, 8) void k_all(
    const float* __restrict__ z_n, const float* __restrict__ centers,
    const float* __restrict__ rot, const int* __restrict__ src_idx,
    const int* __restrict__ tgt_idx, float* __restrict__ out, int B)
{
  __shared__ float zbuf[2][D_DIM];      // z_global per sample slot
  __shared__ float vbuf[2][D_DIM];      // v = Rt @ zg
  __shared__ float pbuf[2][2][D_DIM];   // stage-B partials [p][s][i]

  const int tid = threadIdx.x;
  const int w = tid >> 6, l = tid & 63;
  const int s = w >> 1, p = w & 1;      // sample slot, wave-within-pair
  const int h = l >> 5, q = l & 31;
  int b = blockIdx.x * 2 + s;
  if (b >= B) b = B - 1;                // tail duplicates write identical values

  const int ct = tgt_idx[b];
  const int cs = src_idx[b];

  // ---- Mobius A (replicated in the pair; p==0 publishes). Lane owns comps 2l,2l+1.
  float2 z = ((const float2*)(z_n + (size_t)b * D_DIM))[l];
  float2 c = ((const float2*)(centers + (size_t)cs * D_DIM))[l];
  {
    float y2p = dpp_sum64(z.x * z.x + z.y * z.y);
    float x2p = dpp_sum64(c.x * c.x + c.y * c.y);
    float cz  = dpp_sum64(c.x * z.x + c.y * z.y);
    float sz = 1.0f, y2 = y2p;
    if (y2p > MN2) { sz = MAXNORM / sqrtf(y2p); y2 = MN2; }
    float sc = 1.0f, x2 = x2p;
    if (x2p > MN2) { sc = MAXNORM / sqrtf(x2p); x2 = MN2; }
    float xy  = -(sc * sz) * cz;        // x = -c_source
    float nx  = 1.0f + 2.0f * xy + y2;
    float ny  = 1.0f - x2;
    float inv = 1.0f / fmaxf(1.0f + 2.0f * xy + x2 * y2, 1e-15f);
    float2 zg;
    zg.x = (nx * (-sc * c.x) + ny * (sz * z.x)) * inv;
    zg.y = (nx * (-sc * c.y) + ny * (sz * z.y)) * inv;
    if (p == 0) ((float2*)zbuf[s])[l] = zg;
  }
  __syncthreads();

  // ---- Stage A: v = Rt @ zg. Wave p owns rows [64p,64p+64), 2 rows/iter.
  {
    const float* Rt = rot + (size_t)ct * D_DIM * D_DIM;
    const f32x4 zc = *(const f32x4*)&zbuf[s][4 * q];
#pragma unroll 8
    for (int t = 0; t < 32; ++t) {
      const int r = 64 * p + 2 * t + h;
      f32x4 rr = *(const f32x4*)&Rt[(size_t)r * D_DIM + 4 * q];
      float pv = fmaf(rr[3], zc[3], fmaf(rr[2], zc[2], fmaf(rr[1], zc[1], rr[0] * zc[0])));
      pv = dpp_sum32(pv);
      if (q == 31) vbuf[s][r] = pv;
    }
  }
  __syncthreads();

  // ---- Stage B: w_i = sum_j Rs[j][i] v_j. Wave p owns j in [64p,64p+64).
  // unroll 16 (was 8): ~12 instr/iter gave only ~190cyc of issued work per 8
  // outstanding loads vs ~300cyc L2 latency -> latency-starved (r24 evidence:
  // halving traffic didn't help, so stalls not BW). 16 outstanding covers it.
  {
    const float* Rs = rot + (size_t)cs * D_DIM * D_DIM;
    f32x4 acc = {0.0f, 0.0f, 0.0f, 0.0f};
#pragma unroll 16
    for (int t = 0; t < 32; ++t) {
      const int j = 64 * p + 2 * t + h;
      f32x4 rr = *(const f32x4*)&Rs[(size_t)j * D_DIM + 4 * q];
      float vj = vbuf[s][j];
      acc[0] = fmaf(rr[0], vj, acc[0]);
      acc[1] = fmaf(rr[1], vj, acc[1]);
      acc[2] = fmaf(rr[2], vj, acc[2]);
      acc[3] = fmaf(rr[3], vj, acc[3]);
    }
#pragma unroll
    for (int m = 0; m < 4; ++m) acc[m] += __shfl_xor(acc[m], 32, 64);
    if (h == 0) *(f32x4*)&pbuf[p][s][4 * q] = acc;
  }
  __syncthreads();

  // ---- Mobius B + final projection (replicated in pair; p==0 stores).
  {
    float2 w0 = ((const float2*)pbuf[0][s])[l];
    float2 w1 = ((const float2*)pbuf[1][s])[l];
    float2 wv; wv.x = w0.x + w1.x; wv.y = w0.y + w1.y;
    float2 t = ((const float2*)(centers + (size_t)ct * D_DIM))[l];

    float t2p = dpp_sum64(t.x * t.x + t.y * t.y);
    float w2  = dpp_sum64(wv.x * wv.x + wv.y * wv.y);
    float tw  = dpp_sum64(t.x * wv.x + t.y * wv.y);
    float st = 1.0f, x2 = t2p;
    if (t2p > MN2) { st = MAXNORM / sqrtf(t2p); x2 = MN2; }
    float xy  = st * tw;                // x = +c_target
    float nx  = 1.0f + 2.0f * xy + w2;
    float ny  = 1.0f - x2;
    float inv = 1.0f / fmaxf(1.0f + 2.0f * xy + x2 * w2, 1e-15f);
    float o0 = (nx * (st * t.x) + ny * wv.x) * inv;
    float o1 = (nx * (st * t.y) + ny * wv.y) * inv;

    float no2 = dpp_sum64(o0 * o0 + o1 * o1);
    if (no2 > MN2) { float sc = MAXNORM / sqrtf(no2); o0 *= sc; o1 *= sc; }

    if (p == 0) {
      float2 o; o.x = o0; o.y = o1;
      ((float2*)(out + (size_t)b * D_DIM))[l] = o;
    }
  }
}

extern "C" void kernel_launch(void* const* d_in, const int* in_sizes, int n_in,
                              void* d_out, int out_size, void* d_ws, size_t ws_size,
                              hipStream_t stream) {
  const float* z_n     = (const float*)d_in[0];
  const float* centers = (const float*)d_in[1];
  const float* rot     = (const float*)d_in[2];
  const int*   src     = (const int*)d_in[3];
  const int*   tgt     = (const int*)d_in[4];
  float* out = (float*)d_out;
  const int B = in_sizes[3];

  const int blocks = (B + 1) / 2;       // 2 samples per block
  k_all<<<dim3(blocks), dim3(256), 0, stream>>>(z_n, centers, rot, src, tgt, out, B);
}